// Round 1
// 390.341 us; speedup vs baseline: 1.0314x; 1.0314x over previous
//
#include <hip/hip_runtime.h>
#include <hip/hip_bf16.h>

// Attention: x[8,2048,1024] fp32, W_qkv[1024,3072] fp32, b_qkv[3072] fp32 -> out[8,2048,1024] fp32
// 256x256-tile 8-phase counted-vmcnt bf16 GEMMs (m201 template): BK=64, 8 waves (2Mx4N),
// double-buffered LDS (128 KiB), 4 phases/K-tile, 2x global_load_lds staged per phase,
// s_waitcnt vmcnt(6) once per K-tile (3 half-tiles stay in flight across barriers).
// Hazard ordering: sub-unit staged in phase p only overwrites LDS regions last read in
// phases < p (A_m0:p0->staged p1, B_n01:p0->p2, A_m1:p2->p3, B_n23(t+1):->p0 other buf).
// Fused softmax: QK^T epilogue writes E=exp(S) bf16 + atomic fp32 row sums; PV normalizes.

typedef __attribute__((ext_vector_type(8))) short bf16x8;
typedef __attribute__((ext_vector_type(4))) float f32x4;
typedef __attribute__((ext_vector_type(8))) unsigned short u16x8;
typedef __attribute__((address_space(1))) const unsigned int gu32;
typedef __attribute__((address_space(3))) unsigned int lu32;

__device__ __forceinline__ unsigned short f2bf(float f) {
  union { float f; unsigned int u; } v; v.f = f;
  unsigned int r = v.u + 0x7fffu + ((v.u >> 16) & 1u);  // RNE
  return (unsigned short)(r >> 16);
}
__device__ __forceinline__ void cp16(const unsigned short* g, unsigned short* l) {
  __builtin_amdgcn_global_load_lds((gu32*)g, (lu32*)l, 16, 0, 0);
}

// ---- merged prep: x->xb bf16 (blocks 0..8191), W->Wt transpose (8192..8959), rowsum=0 (8960..9023)
__global__ __launch_bounds__(256) void prep(const float* __restrict__ x,
                                            unsigned short* __restrict__ xb,
                                            const float* __restrict__ W,
                                            unsigned short* __restrict__ Wt,
                                            float* __restrict__ rowsum) {
  __shared__ unsigned short tile[64][72];
  int bid = blockIdx.x, t = threadIdx.x;
  if (bid < 8192) {
    long i = ((long)bid * 256 + t) * 8;
    float4 a = *(const float4*)(x + i);
    float4 b = *(const float4*)(x + i + 4);
    u16x8 o;
    o[0] = f2bf(a.x); o[1] = f2bf(a.y); o[2] = f2bf(a.z); o[3] = f2bf(a.w);
    o[4] = f2bf(b.x); o[5] = f2bf(b.y); o[6] = f2bf(b.z); o[7] = f2bf(b.w);
    *(u16x8*)(xb + i) = o;
  } else if (bid < 8960) {
    int wb = bid - 8192;
    int fb = wb % 48, db = wb / 48;
#pragma unroll
    for (int it = 0; it < 4; it++) {
      int c = t + it * 256;
      int r = c >> 4, c4 = (c & 15) * 4;
      float4 v = *(const float4*)(W + (long)(db * 64 + r) * 3072 + fb * 64 + c4);
      tile[r][c4 + 0] = f2bf(v.x); tile[r][c4 + 1] = f2bf(v.y);
      tile[r][c4 + 2] = f2bf(v.z); tile[r][c4 + 3] = f2bf(v.w);
    }
    __syncthreads();
#pragma unroll
    for (int it = 0; it < 2; it++) {
      int c = t + it * 256;
      int r2 = c >> 3, k8 = (c & 7) * 8;
      u16x8 o;
#pragma unroll
      for (int j = 0; j < 8; j++) o[j] = tile[k8 + j][r2];
      *(u16x8*)(Wt + (long)(fb * 64 + r2) * 1024 + db * 64 + k8) = o;
    }
  } else {
    rowsum[(bid - 8960) * 256 + t] = 0.f;
  }
}

// ---- NT bf16 GEMM, 256x256 tile, BK=64, 8-phase counted-vmcnt pipeline ----
// C[M,Ncols] = A[M,K]*B[Ncols,K]^T, K must be a multiple of 128 and K/64 a power of two.
// MODE 1: QKV epilogue: bf16(acc + bias[f]) -> Q,K row-major; V written TRANSPOSED to Vt[b][d][n]
// MODE 3: E = bf16(exp(acc*scale)); fp32 row-sum partials atomicAdd'ed to rsum
// MODE 4: fp32 C = acc / rsum[row]  (PV -> out)
// SWZ: 0 = plain 2D grid (x=n,y=m); else n-tile count, grid.x flattened, 4x4 super-tiles.
template <int MODE, int SWZ>
__global__ __launch_bounds__(512, 2) void gemm256(
    const unsigned short* __restrict__ A, const unsigned short* __restrict__ B,
    float* __restrict__ C, const float* __restrict__ bias, int Ncols, int K, float scale,
    unsigned short* __restrict__ qp, unsigned short* __restrict__ kp,
    unsigned short* __restrict__ vp, float* __restrict__ rsum,
    long strA, long strB, long strC) {
  __shared__ __align__(16) unsigned short As[2][256 * 64];
  __shared__ __align__(16) unsigned short Bs[2][256 * 64];
  const int tid = threadIdx.x;
  const int lane = tid & 63, wave = tid >> 6;
  const int quad = lane >> 4, l16 = lane & 15;
  const int lr = lane >> 3, lc = lane & 7;
  const int bz = blockIdx.z;
  int mt, nt;
  if (SWZ == 0) {
    mt = blockIdx.y; nt = blockIdx.x;
  } else {
    int bid = blockIdx.x;
    int w = bid & 15, st = bid >> 4;
    constexpr int NSUP = (SWZ >= 4) ? (SWZ / 4) : 1;
    mt = (st / NSUP) * 4 + (w >> 2);
    nt = (st % NSUP) * 4 + (w & 3);
  }
  const long m0 = (long)mt * 256;
  const int n0 = nt * 256;
  const int wm128 = (wave >> 2) * 128;   // wave's 128-row A stripe
  const int wn64 = (wave & 3) * 64;      // wave's 64-row B stripe
  const int NT = K >> 6, mask = NT - 1;  // NT = 16 or 32 here (pow2)

  const unsigned short* __restrict__ Ab = A + (long)bz * strA;
  const unsigned short* __restrict__ Bb = B + (long)bz * strB;

  // staging sub-units (8 KB = 1 cp16/thread each), stream order per K-tile:
  //   A: m0a{0,32} m0b{128,160} m1a{64,96} m1b{192,224}
  //   B: n01a{0,64} n01b{128,192} n23a{32,96} n23b{160,224}
  // (first base: waves 0-3, second: waves 4-7; each wave stages 8 rows x 128B)
  unsigned int aSrc[4], bSrc[4];
  int aOff[4], bOff[4];
  {
    const int auL[4] = {0, 128, 64, 192}, auH[4] = {32, 160, 96, 224};
    const int buL[4] = {0, 128, 32, 160}, buH[4] = {64, 192, 96, 224};
    const bool wlo = wave < 4;
    const int w8 = (wave & 3) * 8;
    const int sc = (lc ^ lr) * 8;  // pre-swizzled global chunk (LDS stays linear)
#pragma unroll
    for (int u = 0; u < 4; u++) {
      int ra = (wlo ? auL[u] : auH[u]) + w8 + lr;
      int rb = (wlo ? buL[u] : buH[u]) + w8 + lr;
      aSrc[u] = (unsigned int)(((int)m0 + ra) * K + sc);
      bSrc[u] = (unsigned int)((n0 + rb) * K + sc);
      aOff[u] = ra * 64 + lc * 8;
      bOff[u] = rb * 64 + lc * 8;
    }
  }

#define SA(u, bb, tt) cp16(Ab + aSrc[u] + (tt) * 64, &As[bb][aOff[u]])
#define SB(u, bb, tt) cp16(Bb + bSrc[u] + (tt) * 64, &Bs[bb][bOff[u]])

  f32x4 acc[8][4];
  f32x4 zero = {0.f, 0.f, 0.f, 0.f};
#pragma unroll
  for (int i = 0; i < 8; i++)
#pragma unroll
    for (int j = 0; j < 4; j++) acc[i][j] = zero;
  bf16x8 am[4][2], bn[4][2];

  // prologue: tile0 fully + tile1 first 6 sub-units; vmcnt(6) -> tile0 landed
  SA(0, 0, 0); SA(1, 0, 0); SB(0, 0, 0); SB(1, 0, 0);
  SA(2, 0, 0); SA(3, 0, 0); SB(2, 0, 0); SB(3, 0, 0);
  SA(0, 1, 1); SA(1, 1, 1); SB(0, 1, 1); SB(1, 1, 1);
  SA(2, 1, 1); SA(3, 1, 1);
  asm volatile("s_waitcnt vmcnt(6)" ::: "memory");
  __builtin_amdgcn_s_barrier();

#define RD_A(bb, mg)                                                                        \
  _Pragma("unroll") for (int ii = 0; ii < 4; ii++) {                                        \
    int row = wm128 + ((mg) * 4 + ii) * 16 + l16;                                           \
    _Pragma("unroll") for (int h = 0; h < 2; h++)                                           \
      am[ii][h] = *(const bf16x8*)(&As[bb][row * 64 + ((((h << 2) | quad)) ^ (row & 7)) * 8]); \
  }
#define RD_B(bb, ng)                                                                        \
  _Pragma("unroll") for (int jj = 0; jj < 2; jj++) {                                        \
    int row = wn64 + ((ng) * 2 + jj) * 16 + l16;                                            \
    _Pragma("unroll") for (int h = 0; h < 2; h++)                                           \
      bn[(ng) * 2 + jj][h] = *(const bf16x8*)(&Bs[bb][row * 64 + ((((h << 2) | quad)) ^ (row & 7)) * 8]); \
  }
#define MM(mg, ng)                                                                          \
  _Pragma("unroll") for (int ii = 0; ii < 4; ii++)                                          \
    _Pragma("unroll") for (int jj = 0; jj < 2; jj++)                                        \
      _Pragma("unroll") for (int h = 0; h < 2; h++)                                         \
        acc[(mg) * 4 + ii][(ng) * 2 + jj] = __builtin_amdgcn_mfma_f32_16x16x32_bf16(        \
            am[ii][h], bn[(ng) * 2 + jj][h], acc[(mg) * 4 + ii][(ng) * 2 + jj], 0, 0, 0);
#define BARRIER __builtin_amdgcn_s_barrier()
#define LGKM0 asm volatile("s_waitcnt lgkmcnt(0)" ::: "memory")
#define PRIO1 __builtin_amdgcn_s_setprio(1)
#define PRIO0 __builtin_amdgcn_s_setprio(0)

  // 4 phases per K-tile; out-of-range prefetch tiles masked (junk but in-bounds + safe).
#define TILE(bb, tt)                                                                        \
  {                                                                                         \
    const int t1_ = ((tt) + 1) & mask, t2_ = ((tt) + 2) & mask;                             \
    /* p0: (m0,n01); stage (t+1).B_n23 -> other buf */                                      \
    RD_A(bb, 0); RD_B(bb, 0);                                                               \
    SB(2, (bb) ^ 1, t1_); SB(3, (bb) ^ 1, t1_);                                             \
    BARRIER; LGKM0; PRIO1; MM(0, 0); PRIO0; BARRIER;                                        \
    /* p1: (m0,n23); stage (t+2).A_m0 -> this buf (A_m0 last read in p0) */                 \
    RD_B(bb, 1);                                                                            \
    SA(0, bb, t2_); SA(1, bb, t2_);                                                         \
    BARRIER; LGKM0; PRIO1; MM(0, 1); PRIO0; BARRIER;                                        \
    /* p2: (m1,n01); stage (t+2).B_n01 (last read in p0) */                                 \
    RD_A(bb, 1);                                                                            \
    SB(0, bb, t2_); SB(1, bb, t2_);                                                         \
    BARRIER; LGKM0; PRIO1; MM(1, 0); PRIO0; BARRIER;                                        \
    /* p3: (m1,n23); stage (t+2).A_m1 (last read in p2); end-of-tile counted drain */       \
    SA(2, bb, t2_); SA(3, bb, t2_);                                                         \
    BARRIER; PRIO1; MM(1, 1); PRIO0;                                                        \
    asm volatile("s_waitcnt vmcnt(6)" ::: "memory");                                        \
    BARRIER;                                                                                \
  }

#pragma unroll 1
  for (int t = 0; t < NT; t += 2) {
    TILE(0, t);
    TILE(1, t + 1);
  }

  if (MODE == 1) {
#pragma unroll
    for (int j = 0; j < 4; j++) {
      int fg = n0 + wn64 + j * 16 + l16;  // 64-col stripe never straddles Q/K/V bounds
      float bv = bias[fg];
      if (fg < 2048) {
        unsigned short* outp = (fg < 1024) ? qp : kp;
        int fo = fg & 1023;
#pragma unroll
        for (int i = 0; i < 8; i++)
#pragma unroll
          for (int r = 0; r < 4; r++) {
            long trow = m0 + wm128 + i * 16 + quad * 4 + r;
            outp[trow * 1024 + fo] = f2bf(acc[i][j][r] + bv);
          }
      } else {
        int d = fg - 2048;  // Vt[b][d][n]
#pragma unroll
        for (int i = 0; i < 8; i++)
#pragma unroll
          for (int r = 0; r < 4; r++) {
            long trow = m0 + wm128 + i * 16 + quad * 4 + r;
            vp[((long)(trow >> 11) * 1024 + d) * 2048 + (trow & 2047)] = f2bf(acc[i][j][r] + bv);
          }
      }
    }
  } else if (MODE == 3) {
    unsigned short* Co = qp + (long)bz * strC;
    float* rs = rsum + bz * 2048;
#pragma unroll
    for (int i = 0; i < 8; i++)
#pragma unroll
      for (int r = 0; r < 4; r++) {
        long gm = m0 + wm128 + i * 16 + quad * 4 + r;
        float psum = 0.f;
#pragma unroll
        for (int j = 0; j < 4; j++) {
          float e = __expf(acc[i][j][r] * scale);
          psum += e;
          Co[gm * Ncols + n0 + wn64 + j * 16 + l16] = f2bf(e);
        }
        psum += __shfl_xor(psum, 1);
        psum += __shfl_xor(psum, 2);
        psum += __shfl_xor(psum, 4);
        psum += __shfl_xor(psum, 8);
        if (l16 == 0) atomicAdd(rs + gm, psum);
      }
  } else {
    float* Co = C + (long)bz * strC;
    const float* rs = rsum + bz * 2048;
#pragma unroll
    for (int i = 0; i < 8; i++)
#pragma unroll
      for (int r = 0; r < 4; r++) {
        long gm = m0 + wm128 + i * 16 + quad * 4 + r;
        float inv = 1.0f / rs[gm];
#pragma unroll
        for (int j = 0; j < 4; j++)
          Co[gm * Ncols + n0 + wn64 + j * 16 + l16] = acc[i][j][r] * inv;
      }
  }
  // drain any in-flight junk prefetches before LDS is released to another block
  asm volatile("s_waitcnt vmcnt(0)" ::: "memory");
#undef SA
#undef SB
#undef RD_A
#undef RD_B
#undef MM
#undef TILE
#undef BARRIER
#undef LGKM0
#undef PRIO1
#undef PRIO0
}

extern "C" void kernel_launch(void* const* d_in, const int* in_sizes, int n_in,
                              void* d_out, int out_size, void* d_ws, size_t ws_size,
                              hipStream_t stream) {
  const float* x = (const float*)d_in[0];
  const float* W = (const float*)d_in[1];
  const float* bq = (const float*)d_in[2];
  float* out = (float*)d_out;
  char* ws = (char*)d_ws;
  const long MB = 1L << 20;
  // Persistent: Q 0-32, K 32-64, Vt 64-96.
  // Phase A scratch: xb 96-128, Wt 128-134 (dead after QKV).
  // Phase B scratch: E bf16 96-160 (overlaps dead xb/Wt). rowsum 160 MB (64 KB).
  unsigned short* Q  = (unsigned short*)(ws);
  unsigned short* Kb = (unsigned short*)(ws + 32 * MB);
  unsigned short* Vt = (unsigned short*)(ws + 64 * MB);
  unsigned short* xb = (unsigned short*)(ws + 96 * MB);
  unsigned short* Wt = (unsigned short*)(ws + 128 * MB);
  unsigned short* E  = (unsigned short*)(ws + 96 * MB);
  float* rowsum      = (float*)(ws + 160 * MB);  // 8*2048 fp32 = 64 KB

  prep<<<9024, 256, 0, stream>>>(x, xb, W, Wt, rowsum);
  // QKV: [16384,3072] = xb[16384,1024] @ Wt[3072,1024]^T ; 64x12 tiles, 4x4 super-tiles
  gemm256<1, 12><<<dim3(768, 1, 1), 512, 0, stream>>>(xb, Wt, nullptr, bq, 3072, 1024, 1.0f,
                                                      Q, Kb, Vt, nullptr, 0, 0, 0);
  // E = exp((Q K^T) * scale) bf16 + rowsum atomics; 8x8 tiles/batch, 4x4 super-tiles
  gemm256<3, 8><<<dim3(64, 1, 8), 512, 0, stream>>>(Q, Kb, nullptr, nullptr, 2048, 1024,
                                                    0.03125f, E, nullptr, nullptr, rowsum,
                                                    2048L * 1024, 2048L * 1024, 2048L * 2048);
  // out = (E @ Vt^T) / rowsum, fp32; 8x4 tiles/batch
  gemm256<4, 4><<<dim3(32, 1, 8), 512, 0, stream>>>(E, Vt, out, nullptr, 1024, 2048, 1.0f,
                                                    nullptr, nullptr, nullptr, rowsum,
                                                    2048L * 2048, 1024L * 2048, 2048L * 1024);
}

// Round 3
// 381.865 us; speedup vs baseline: 1.0543x; 1.0222x over previous
//
#include <hip/hip_runtime.h>
#include <hip/hip_bf16.h>

// Attention: x[8,2048,1024] fp32, W_qkv[1024,3072] fp32, b_qkv[3072] fp32 -> out[8,2048,1024] fp32
// 256x256-tile bf16 GEMMs, 4 phases/K-tile. Phase = {lgkmcnt(0); read-ahead; s_barrier(asm);
// stage(global_load_lds); MFMA}. Read-ahead issued one phase before use -> drain is free;
// lgkmcnt(0) is count-independent (r2's lgkmcnt(4) miscount/race caused absmax 0.052).
// Stage invariant: a region is staged only AFTER a barrier that post-dates every wave's
// lgkmcnt(0)-drain of that region's readers; same-phase read-ahead targets are region-disjoint
// from the phase's stage targets. vmcnt(4) once per K-tile (pre-barrier @p2) => tile t+1 fully
// landed before p3 reads buf^1; tile t+2's 4 in-flight stages ride across barriers.
// Fused softmax: QK^T epilogue writes E=exp(S) bf16 + atomic fp32 row sums; PV normalizes.

typedef __attribute__((ext_vector_type(8))) short bf16x8;
typedef __attribute__((ext_vector_type(4))) float f32x4;
typedef __attribute__((ext_vector_type(8))) unsigned short u16x8;
typedef __attribute__((address_space(1))) const unsigned int gu32;
typedef __attribute__((address_space(3))) unsigned int lu32;

__device__ __forceinline__ unsigned short f2bf(float f) {
  union { float f; unsigned int u; } v; v.f = f;
  unsigned int r = v.u + 0x7fffu + ((v.u >> 16) & 1u);  // RNE
  return (unsigned short)(r >> 16);
}
__device__ __forceinline__ void cp16(const unsigned short* g, unsigned short* l) {
  __builtin_amdgcn_global_load_lds((gu32*)g, (lu32*)l, 16, 0, 0);
}

// ---- merged prep: x->xb bf16 (blocks 0..8191), W->Wt transpose (8192..8959), rowsum=0 (8960..9023)
__global__ __launch_bounds__(256) void prep(const float* __restrict__ x,
                                            unsigned short* __restrict__ xb,
                                            const float* __restrict__ W,
                                            unsigned short* __restrict__ Wt,
                                            float* __restrict__ rowsum) {
  __shared__ unsigned short tile[64][72];
  int bid = blockIdx.x, t = threadIdx.x;
  if (bid < 8192) {
    long i = ((long)bid * 256 + t) * 8;
    float4 a = *(const float4*)(x + i);
    float4 b = *(const float4*)(x + i + 4);
    u16x8 o;
    o[0] = f2bf(a.x); o[1] = f2bf(a.y); o[2] = f2bf(a.z); o[3] = f2bf(a.w);
    o[4] = f2bf(b.x); o[5] = f2bf(b.y); o[6] = f2bf(b.z); o[7] = f2bf(b.w);
    *(u16x8*)(xb + i) = o;
  } else if (bid < 8960) {
    int wb = bid - 8192;
    int fb = wb % 48, db = wb / 48;
#pragma unroll
    for (int it = 0; it < 4; it++) {
      int c = t + it * 256;
      int r = c >> 4, c4 = (c & 15) * 4;
      float4 v = *(const float4*)(W + (long)(db * 64 + r) * 3072 + fb * 64 + c4);
      tile[r][c4 + 0] = f2bf(v.x); tile[r][c4 + 1] = f2bf(v.y);
      tile[r][c4 + 2] = f2bf(v.z); tile[r][c4 + 3] = f2bf(v.w);
    }
    __syncthreads();
#pragma unroll
    for (int it = 0; it < 2; it++) {
      int c = t + it * 256;
      int r2 = c >> 3, k8 = (c & 7) * 8;
      u16x8 o;
#pragma unroll
      for (int j = 0; j < 8; j++) o[j] = tile[k8 + j][r2];
      *(u16x8*)(Wt + (long)(fb * 64 + r2) * 1024 + db * 64 + k8) = o;
    }
  } else {
    rowsum[(bid - 8960) * 256 + t] = 0.f;
  }
}

// ---- NT bf16 GEMM, 256x256 tile, BK=64, read-ahead 4-phase pipeline ----
// C[M,Ncols] = A[M,K]*B[Ncols,K]^T, K/64 a power of two (16 or 32 here).
// MODE 1: QKV epilogue: bf16(acc + bias[f]) -> Q,K row-major; V written TRANSPOSED to Vt[b][d][n]
// MODE 3: E = bf16(exp(acc*scale)); fp32 row-sum partials atomicAdd'ed to rsum
// MODE 4: fp32 C = acc / rsum[row]  (PV -> out)
// SWZ: 0 = plain 2D grid (x=n,y=m); else n-tile count, grid.x flattened, 4x4 super-tiles.
template <int MODE, int SWZ>
__global__ __launch_bounds__(512, 2) void gemm256(
    const unsigned short* __restrict__ A, const unsigned short* __restrict__ B,
    float* __restrict__ C, const float* __restrict__ bias, int Ncols, int K, float scale,
    unsigned short* __restrict__ qp, unsigned short* __restrict__ kp,
    unsigned short* __restrict__ vp, float* __restrict__ rsum,
    long strA, long strB, long strC) {
  __shared__ __align__(16) unsigned short As[2][256 * 64];
  __shared__ __align__(16) unsigned short Bs[2][256 * 64];
  const int tid = threadIdx.x;
  const int lane = tid & 63, wave = tid >> 6;
  const int quad = lane >> 4, l16 = lane & 15;
  const int lr = lane >> 3, lc = lane & 7;
  const int bz = blockIdx.z;
  int mt, nt;
  if (SWZ == 0) {
    mt = blockIdx.y; nt = blockIdx.x;
  } else {
    int bid = blockIdx.x;
    int w = bid & 15, st = bid >> 4;
    constexpr int NSUP = (SWZ >= 4) ? (SWZ / 4) : 1;
    mt = (st / NSUP) * 4 + (w >> 2);
    nt = (st % NSUP) * 4 + (w & 3);
  }
  const long m0 = (long)mt * 256;
  const int n0 = nt * 256;
  const int wm128 = (wave >> 2) * 128;   // wave's 128-row A stripe
  const int wn64 = (wave & 3) * 64;      // wave's 64-row B stripe
  const int NT = K >> 6, mask = NT - 1;

  const unsigned short* __restrict__ Ab = A + (long)bz * strA;
  const unsigned short* __restrict__ Bb = B + (long)bz * strB;

  // staging sub-units (8 KB = 1 cp16/thread each):
  //   A units: 0={rows 0-63}, 1={128-191}, 2={64-127}, 3={192-255}
  //   B units: 0={0-31,64-95}, 1={128-159,192-223}, 2={32-63,96-127}, 3={160-191,224-255}
  unsigned int aSrc[4], bSrc[4];
  int aOff[4], bOff[4];
  {
    const int auL[4] = {0, 128, 64, 192}, auH[4] = {32, 160, 96, 224};
    const int buL[4] = {0, 128, 32, 160}, buH[4] = {64, 192, 96, 224};
    const bool wlo = wave < 4;
    const int w8 = (wave & 3) * 8;
    const int sc = (lc ^ lr) * 8;  // pre-swizzled global chunk (LDS stays linear)
#pragma unroll
    for (int u = 0; u < 4; u++) {
      int ra = (wlo ? auL[u] : auH[u]) + w8 + lr;
      int rb = (wlo ? buL[u] : buH[u]) + w8 + lr;
      aSrc[u] = (unsigned int)(((int)m0 + ra) * K + sc);
      bSrc[u] = (unsigned int)((n0 + rb) * K + sc);
      aOff[u] = ra * 64 + lc * 8;
      bOff[u] = rb * 64 + lc * 8;
    }
  }

#define SA(u, bb, tt) cp16(Ab + aSrc[u] + (tt) * 64, &As[bb][aOff[u]])
#define SB(u, bb, tt) cp16(Bb + bSrc[u] + (tt) * 64, &Bs[bb][bOff[u]])

  f32x4 acc[8][4];
  f32x4 zero = {0.f, 0.f, 0.f, 0.f};
#pragma unroll
  for (int i = 0; i < 8; i++)
#pragma unroll
    for (int j = 0; j < 4; j++) acc[i][j] = zero;
  bf16x8 am[2][2][2];  // [regbuf][frag][half] - A quarter double-buffer
  bf16x8 bn[4][2];     // [frag][half]         - full B stripe, 1 K-tile

  // ds-read: quarter q (2 m-frags, rows q*32..q*32+31 of stripe) of buf bb into regbuf d
#define RD_AQ(d, bb, q)                                                                     \
  _Pragma("unroll") for (int ii = 0; ii < 2; ii++) {                                        \
    int row = wm128 + ((q) * 2 + ii) * 16 + l16;                                            \
    _Pragma("unroll") for (int h = 0; h < 2; h++)                                           \
      am[d][ii][h] = *(const bf16x8*)(&As[bb][row * 64 + ((((h << 2) | quad)) ^ (row & 7)) * 8]); \
  }
  // ds-read: all 4 B frags of buf bb
#define RD_BALL(bb)                                                                         \
  _Pragma("unroll") for (int jj = 0; jj < 4; jj++) {                                        \
    int row = wn64 + jj * 16 + l16;                                                         \
    _Pragma("unroll") for (int h = 0; h < 2; h++)                                           \
      bn[jj][h] = *(const bf16x8*)(&Bs[bb][row * 64 + ((((h << 2) | quad)) ^ (row & 7)) * 8]); \
  }
  // MFMA: quarter q from regbuf d x all B frags (16 MFMA)
#define MMQ(q, d)                                                                           \
  _Pragma("unroll") for (int ii = 0; ii < 2; ii++)                                          \
    _Pragma("unroll") for (int jj = 0; jj < 4; jj++)                                        \
      _Pragma("unroll") for (int h = 0; h < 2; h++)                                         \
        acc[(q) * 2 + ii][jj] = __builtin_amdgcn_mfma_f32_16x16x32_bf16(                    \
            am[d][ii][h], bn[jj][h], acc[(q) * 2 + ii][jj], 0, 0, 0);
#define ABAR asm volatile("s_barrier" ::: "memory")
#define LGKM0 asm volatile("s_waitcnt lgkmcnt(0)" ::: "memory")
#define VMCNT4 asm volatile("s_waitcnt vmcnt(4)" ::: "memory")
#define PRIO1 __builtin_amdgcn_s_setprio(1)
#define PRIO0 __builtin_amdgcn_s_setprio(0)

  // Phase = {LGKM0 (drain prev read-ahead; all this wave's older reads done);
  //          issue read-ahead; ABAR (=> ALL waves' older reads done);
  //          stage (safe: its region's readers all drained pre-barrier); MFMA}.
  // Same-phase read-ahead is region-disjoint from the stage target:
  //   p0: RD q1 (A u0/u1-hi)  vs SB01 (B lo)      p1: RD q2 (A u2/u3-lo) vs SA01 (A u0,u1)
  //   p2: RD q3 (A u2/u3-hi)  vs SB23 (B hi)      p3: RD buf^1           vs SA23 (A u2,u3 of buf)
  // VMCNT4 @p2 pre-barrier: tile t+1's 8 loads landed (4 of t+2's remain in flight);
  // barrier(p2) makes that landing visible to all waves before p3 reads buf^1.
  // p3 runs MFMA q3 BEFORE RD_BALL so old/new bn never co-live (reg pressure).
  // Out-of-range prefetch tiles masked (junk but in-bounds; obeys same WAR discipline).
#define TILE(bb, tt)                                                                        \
  {                                                                                         \
    const int t2_ = ((tt) + 2) & mask;                                                      \
    /* p0 */                                                                                \
    LGKM0; RD_AQ(1, bb, 1); ABAR;                                                           \
    SB(0, bb, t2_); SB(1, bb, t2_);                                                         \
    PRIO1; MMQ(0, 0); PRIO0;                                                                \
    /* p1 */                                                                                \
    LGKM0; RD_AQ(0, bb, 2); ABAR;                                                           \
    SA(0, bb, t2_); SA(1, bb, t2_);                                                         \
    PRIO1; MMQ(1, 1); PRIO0;                                                                \
    /* p2 */                                                                                \
    LGKM0; RD_AQ(1, bb, 3); VMCNT4; ABAR;                                                   \
    SB(2, bb, t2_); SB(3, bb, t2_);                                                         \
    PRIO1; MMQ(2, 0); PRIO0;                                                                \
    /* p3 */                                                                                \
    LGKM0; RD_AQ(0, (bb) ^ 1, 0);                                                           \
    PRIO1; MMQ(3, 1); PRIO0;                                                                \
    RD_BALL((bb) ^ 1);                                                                      \
    ABAR;                                                                                   \
    SA(2, bb, t2_); SA(3, bb, t2_);                                                         \
  }

  // prologue: stage tile0 + tile1 fully; land tile0 (all waves); read tile0's q0 + B
  SA(0, 0, 0); SA(1, 0, 0); SB(0, 0, 0); SB(1, 0, 0);
  SA(2, 0, 0); SA(3, 0, 0); SB(2, 0, 0); SB(3, 0, 0);
  SA(0, 1, 1); SA(1, 1, 1); SB(0, 1, 1); SB(1, 1, 1);
  SA(2, 1, 1); SA(3, 1, 1); SB(2, 1, 1); SB(3, 1, 1);
  asm volatile("s_waitcnt vmcnt(8)" ::: "memory");
  ABAR;
  RD_AQ(0, 0, 0);
  RD_BALL(0);

#pragma unroll 1
  for (int t = 0; t < NT; t += 2) {
    TILE(0, t);
    TILE(1, t + 1);
  }

  if (MODE == 1) {
#pragma unroll
    for (int j = 0; j < 4; j++) {
      int fg = n0 + wn64 + j * 16 + l16;  // 64-col stripe never straddles Q/K/V bounds
      float bv = bias[fg];
      if (fg < 2048) {
        unsigned short* outp = (fg < 1024) ? qp : kp;
        int fo = fg & 1023;
#pragma unroll
        for (int i = 0; i < 8; i++)
#pragma unroll
          for (int r = 0; r < 4; r++) {
            long trow = m0 + wm128 + i * 16 + quad * 4 + r;
            outp[trow * 1024 + fo] = f2bf(acc[i][j][r] + bv);
          }
      } else {
        int d = fg - 2048;  // Vt[b][d][n]
#pragma unroll
        for (int i = 0; i < 8; i++)
#pragma unroll
          for (int r = 0; r < 4; r++) {
            long trow = m0 + wm128 + i * 16 + quad * 4 + r;
            vp[((long)(trow >> 11) * 1024 + d) * 2048 + (trow & 2047)] = f2bf(acc[i][j][r] + bv);
          }
      }
    }
  } else if (MODE == 3) {
    unsigned short* Co = qp + (long)bz * strC;
    float* rs = rsum + bz * 2048;
#pragma unroll
    for (int i = 0; i < 8; i++)
#pragma unroll
      for (int r = 0; r < 4; r++) {
        long gm = m0 + wm128 + i * 16 + quad * 4 + r;
        float psum = 0.f;
#pragma unroll
        for (int j = 0; j < 4; j++) {
          float e = __expf(acc[i][j][r] * scale);
          psum += e;
          Co[gm * Ncols + n0 + wn64 + j * 16 + l16] = f2bf(e);
        }
        psum += __shfl_xor(psum, 1);
        psum += __shfl_xor(psum, 2);
        psum += __shfl_xor(psum, 4);
        psum += __shfl_xor(psum, 8);
        if (l16 == 0) atomicAdd(rs + gm, psum);
      }
  } else {
    float* Co = C + (long)bz * strC;
    const float* rs = rsum + bz * 2048;
#pragma unroll
    for (int i = 0; i < 8; i++)
#pragma unroll
      for (int r = 0; r < 4; r++) {
        long gm = m0 + wm128 + i * 16 + quad * 4 + r;
        float inv = 1.0f / rs[gm];
#pragma unroll
        for (int j = 0; j < 4; j++)
          Co[gm * Ncols + n0 + wn64 + j * 16 + l16] = acc[i][j][r] * inv;
      }
  }
  // drain in-flight junk prefetches + junk ds_reads before block exit
  asm volatile("s_waitcnt vmcnt(0) lgkmcnt(0)" ::: "memory");
#undef SA
#undef SB
#undef RD_AQ
#undef RD_BALL
#undef MMQ
#undef TILE
#undef ABAR
#undef LGKM0
#undef VMCNT4
#undef PRIO1
#undef PRIO0
}

extern "C" void kernel_launch(void* const* d_in, const int* in_sizes, int n_in,
                              void* d_out, int out_size, void* d_ws, size_t ws_size,
                              hipStream_t stream) {
  const float* x = (const float*)d_in[0];
  const float* W = (const float*)d_in[1];
  const float* bq = (const float*)d_in[2];
  float* out = (float*)d_out;
  char* ws = (char*)d_ws;
  const long MB = 1L << 20;
  // Persistent: Q 0-32, K 32-64, Vt 64-96.
  // Phase A scratch: xb 96-128, Wt 128-134 (dead after QKV).
  // Phase B scratch: E bf16 96-160 (overlaps dead xb/Wt). rowsum 160 MB (64 KB).
  unsigned short* Q  = (unsigned short*)(ws);
  unsigned short* Kb = (unsigned short*)(ws + 32 * MB);
  unsigned short* Vt = (unsigned short*)(ws + 64 * MB);
  unsigned short* xb = (unsigned short*)(ws + 96 * MB);
  unsigned short* Wt = (unsigned short*)(ws + 128 * MB);
  unsigned short* E  = (unsigned short*)(ws + 96 * MB);
  float* rowsum      = (float*)(ws + 160 * MB);  // 8*2048 fp32 = 64 KB

  prep<<<9024, 256, 0, stream>>>(x, xb, W, Wt, rowsum);
  // QKV: [16384,3072] = xb[16384,1024] @ Wt[3072,1024]^T ; 64x12 tiles, 4x4 super-tiles
  gemm256<1, 12><<<dim3(768, 1, 1), 512, 0, stream>>>(xb, Wt, nullptr, bq, 3072, 1024, 1.0f,
                                                      Q, Kb, Vt, nullptr, 0, 0, 0);
  // E = exp((Q K^T) * scale) bf16 + rowsum atomics; 8x8 tiles/batch, 4x4 super-tiles
  gemm256<3, 8><<<dim3(64, 1, 8), 512, 0, stream>>>(Q, Kb, nullptr, nullptr, 2048, 1024,
                                                    0.03125f, E, nullptr, nullptr, rowsum,
                                                    2048L * 1024, 2048L * 1024, 2048L * 2048);
  // out = (E @ Vt^T) / rowsum, fp32; 8x4 tiles/batch
  gemm256<4, 4><<<dim3(32, 1, 8), 512, 0, stream>>>(E, Vt, out, nullptr, 1024, 2048, 1.0f,
                                                    nullptr, nullptr, nullptr, rowsum,
                                                    2048L * 2048, 1024L * 2048, 2048L * 1024);
}